// Round 5
// baseline (406.807 us; speedup 1.0000x reference)
//
#include <hip/hip_runtime.h>
#include <cmath>
#include <cstdint>

#define NBATCH 16
#define HH 56
#define WW 56
#define CCH 256
#define NHEADS 8
#define HDIM 32
#define WSP 7
#define NWIN 128
#define LTOK 392
#define NTOK 3136

typedef __attribute__((ext_vector_type(8))) __bf16 bf16x8;
typedef __attribute__((ext_vector_type(4))) __bf16 bf16x4;
typedef __attribute__((ext_vector_type(4))) float f32x4;

static __device__ __forceinline__ uint32_t pkbf(float a, float b) {
    __bf16 x = (__bf16)a, y = (__bf16)b;
    uint16_t xu = __builtin_bit_cast(uint16_t, x);
    uint16_t yu = __builtin_bit_cast(uint16_t, y);
    return (uint32_t)xu | ((uint32_t)yu << 16);
}

// ---------------------------------------------------------------- pack W
__global__ __launch_bounds__(256) void pack_w(const float* __restrict__ w,
                                              __bf16* __restrict__ Wt) {
    int idx = blockIdx.x * blockDim.x + threadIdx.x;
    if (idx >= 9 * CCH * CCH) return;
    int tap = idx / (CCH * CCH);
    int rem = idx % (CCH * CCH);
    int co = rem / CCH, ci = rem % CCH;
    Wt[idx] = (__bf16)(w[(size_t)tap * CCH * CCH + (size_t)ci * CCH + co]);
}

// ---------------------------------------------------------------- LePE conv
// Implicit GEMM. Block = (window, 8-row stripe): M=56 pos (padded 64), N=256.
// A: halo rows in LDS [10][9][264]. B: per-wave async global_load_lds pipeline,
// double-buffered per-wave 4KB LDS slots, counted vmcnt(4), no K-loop barriers.
#define AV_R 10
#define AV_C 9
#define AV_S 264
__global__ __launch_bounds__(256, 2) void lepe_conv(const float* __restrict__ qkv,
        const __bf16* __restrict__ Wt, const float* __restrict__ bconv,
        float* __restrict__ out) {
    const int bid = blockIdx.x;
    const int win = bid / 7, rb = bid % 7;
    const int b = win >> 3, wi = win & 7;
    const int rbase = rb * 8;
    const int tid = threadIdx.x;
    const int lane = tid & 63, wv = tid >> 6;
    const int lr = lane & 15, lg = lane >> 4;
    __shared__ __bf16 Av[AV_R * AV_C * AV_S];   // 47,520 B
    __shared__ __bf16 Bs[2][4][2048];           // 32,768 B
    const float* vsrc = qkv + 2 * (size_t)NBATCH * NTOK * CCH;

    for (int t = tid; t < AV_R * AV_C * 64; t += 256) {
        int rr = t / (AV_C * 64);
        int rem = t % (AV_C * 64);
        int cc = rem / 64, chg = rem % 64;
        int ar = rbase + rr - 1, c = cc - 1;
        f32x4 v = {0.f, 0.f, 0.f, 0.f};
        if (ar >= 0 && ar < HH && c >= 0 && c < WSP) {
            int token = ar * WW + wi * WSP + c;
            v = *(const f32x4*)(vsrc + ((size_t)b * NTOK + token) * CCH + chg * 4);
        }
        bf16x4 w;
#pragma unroll
        for (int i = 0; i < 4; i++) w[i] = (__bf16)v[i];
        *(bf16x4*)&Av[(rr * AV_C + cc) * AV_S + chg * 4] = w;
    }
    __syncthreads();

    f32x4 acc[4][4];
#pragma unroll
    for (int i = 0; i < 4; i++)
#pragma unroll
        for (int j = 0; j < 4; j++) acc[i][j] = (f32x4){0.f, 0.f, 0.f, 0.f};

    int ab[4];
#pragma unroll
    for (int mt = 0; mt < 4; mt++) {
        int p = mt * 16 + lr; if (p > 55) p = 55;
        ab[mt] = ((p / 7) * AV_C + (p % 7)) * AV_S + lg * 8;
    }
    int bro[4];
#pragma unroll
    for (int nt = 0; nt < 4; nt++)
        bro[nt] = (nt * 16 + lr) * 32 + ((lg ^ ((lr >> 1) & 3)) * 8);
    const __bf16* wsrc = Wt + (size_t)(wv * 64 + (lane >> 2)) * CCH
                            + (((lane & 3) ^ ((lane >> 3) & 3)) * 8);
    __bf16* b0 = &Bs[0][wv][0];
    __bf16* b1 = &Bs[1][wv][0];

#define GLDS(gp, lp)                                                        \
    __builtin_amdgcn_global_load_lds(                                       \
        (const __attribute__((address_space(1))) void*)(gp),                \
        (__attribute__((address_space(3))) void*)(lp), 16, 0, 0)
#define ISSUE(s, lb) do {                                                   \
        const int tp_ = (s) >> 3, kq_ = (s) & 7;                            \
        const __bf16* g_ = wsrc + tp_ * (CCH * CCH) + kq_ * 32;             \
        GLDS(g_, lb);                                                       \
        GLDS(g_ + 16 * CCH, (lb) + 512);                                    \
        GLDS(g_ + 32 * CCH, (lb) + 1024);                                   \
        GLDS(g_ + 48 * CCH, (lb) + 1536);                                   \
    } while (0)
#define STEPX(s, lb, doiss, s2) do {                                        \
        const int tap_ = (s) >> 3, ks_ = (s) & 7;                           \
        const int dy_ = (tap_ >= 6) ? 2 : ((tap_ >= 3) ? 1 : 0);            \
        const int offa = (tap_ + 6 * dy_) * AV_S + ks_ * 32;                \
        bf16x8 a_[4], bb_[4];                                               \
        _Pragma("unroll")                                                   \
        for (int mt = 0; mt < 4; mt++)                                      \
            a_[mt] = *(const bf16x8*)&Av[ab[mt] + offa];                    \
        _Pragma("unroll")                                                   \
        for (int nt = 0; nt < 4; nt++)                                      \
            bb_[nt] = *(const bf16x8*)&(lb)[bro[nt]];                       \
        asm volatile("s_waitcnt lgkmcnt(0)" ::: "memory");                  \
        __builtin_amdgcn_sched_barrier(0);                                  \
        if (doiss) ISSUE(s2, lb);                                           \
        _Pragma("unroll")                                                   \
        for (int mt = 0; mt < 4; mt++)                                      \
            _Pragma("unroll")                                               \
            for (int nt = 0; nt < 4; nt++)                                  \
                acc[mt][nt] = __builtin_amdgcn_mfma_f32_16x16x32_bf16(      \
                    a_[mt], bb_[nt], acc[mt][nt], 0, 0, 0);                 \
    } while (0)
#define WAIT4 asm volatile("s_waitcnt vmcnt(4)" ::: "memory")
#define WAIT0 asm volatile("s_waitcnt vmcnt(0)" ::: "memory")

    ISSUE(0, b0);
    ISSUE(1, b1);
    for (int s = 0; s < 70; s += 2) {
        WAIT4; STEPX(s, b0, 1, s + 2);
        WAIT4; STEPX(s + 1, b1, 1, s + 3);
    }
    WAIT4; STEPX(70, b0, 0, 0);
    WAIT0; STEPX(71, b1, 0, 0);
#undef GLDS
#undef ISSUE
#undef STEPX
#undef WAIT4
#undef WAIT0

#pragma unroll
    for (int nt = 0; nt < 4; nt++) {
        int ch = wv * 64 + nt * 16 + lr;
        float bias = bconv[ch];
#pragma unroll
        for (int mt = 0; mt < 4; mt++) {
#pragma unroll
            for (int r = 0; r < 4; r++) {
                int p = mt * 16 + lg * 4 + r;
                if (p < 56) {
                    int ar = rbase + p / 7, c = p % 7;
                    int token = ar * WW + wi * WSP + c;
                    out[((size_t)b * NTOK + token) * CCH + ch] = acc[mt][nt][r] + bias;
                }
            }
        }
    }
}

// ---------------------------------------------------------------- attention
// One block per (win, head), 8 waves, K/V^T staged once (f32->bf16 fused).
// SWAPPED QK^T: s = mfma(K_frag, Q_frag) -> lane owns full q-row (q=lr):
// softmax is in-lane + 2 shfl_xor. Keys in two halves (12+13 tiles) with
// online rescale to keep VGPR <= 128. P bounce: 2x ds_write_b64 + 2x
// ds_read_b64 per 32-key chunk, no asm barriers.
#define KS_R 400
#define KS_S 36
#define VS_S 424
#define PB_S 36
__global__ __launch_bounds__(512, 4) void attn2(const float* __restrict__ qkv,
                                                float* __restrict__ out) {
    const int wh = blockIdx.x;
    const int win = wh >> 3, h = wh & 7;
    const int b = win >> 3, wi = win & 7;
    const int tid = threadIdx.x;
    const int lane = tid & 63, wv = tid >> 6;
    const int lr = lane & 15, lg = lane >> 4;
    const float scale = 0.17677669529663687f;   // 32^-0.5

    __shared__ __bf16 Ks[KS_R * KS_S];          // 28,800 B
    __shared__ __bf16 Vs[HDIM * VS_S];          // 27,136 B
    __shared__ __bf16 Pb[8][16 * PB_S];         //  9,216 B  (total 65,152)

    const size_t plane = (size_t)NBATCH * NTOK * CCH;
    const float* qsrc = qkv + ((size_t)b * NTOK) * CCH + h * HDIM;
    const float* ksrc = qsrc + plane;
    const float* vsrc = qsrc + 2 * plane;

    // ---- stage K: [400 rows][32 ch], rows >=392 zero
    for (int t = tid; t < KS_R * 4; t += 512) {
        int row = t >> 2, g = t & 3;
        bf16x8 val;
        if (row < LTOK) {
            int tok = (row / 7) * WW + wi * WSP + row % 7;
            const float* p = ksrc + (size_t)tok * CCH + g * 8;
            f32x4 a = *(const f32x4*)p;
            f32x4 c = *(const f32x4*)(p + 4);
#pragma unroll
            for (int i = 0; i < 4; i++) { val[i] = (__bf16)a[i]; val[4 + i] = (__bf16)c[i]; }
        } else {
#pragma unroll
            for (int i = 0; i < 8; i++) val[i] = (__bf16)0.0f;
        }
        *(bf16x8*)&Ks[row * KS_S + g * 8] = val;
    }
    // ---- stage V transposed: Vs[ch][key]
    for (int t = tid; t < LTOK * 4; t += 512) {
        int key = t % LTOK, chg = t / LTOK;
        int tok = (key / 7) * WW + wi * WSP + key % 7;
        const float* p = vsrc + (size_t)tok * CCH + chg * 8;
        f32x4 a = *(const f32x4*)p;
        f32x4 c = *(const f32x4*)(p + 4);
#pragma unroll
        for (int i = 0; i < 4; i++) {
            Vs[(chg * 8 + i) * VS_S + key] = (__bf16)a[i];
            Vs[(chg * 8 + 4 + i) * VS_S + key] = (__bf16)0.0f + (__bf16)c[i];
        }
    }
    // zero V pad keys 392..423
    for (int t = tid; t < HDIM * 32; t += 512) {
        int ch = t >> 5, k = t & 31;
        Vs[ch * VS_S + LTOK + k] = (__bf16)0.0f;
    }
    __syncthreads();

    __bf16* pb = Pb[wv];
    for (int tile = wv; tile < 25; tile += 8) {
        // ---- Q fragment (B-operand): lane holds q-col = lr, d = 8*lg+i
        int qrow = tile * 16 + lr;
        int qe = qrow < LTOK ? qrow : LTOK - 1;
        int tokq = (qe / 7) * WW + wi * WSP + qe % 7;
        const float* qp = qsrc + (size_t)tokq * CCH + lg * 8;
        f32x4 qa = *(const f32x4*)qp;
        f32x4 qc = *(const f32x4*)(qp + 4);
        bf16x8 aq;
#pragma unroll
        for (int i = 0; i < 4; i++) {
            aq[i] = (__bf16)(qa[i] * scale);
            aq[4 + i] = (__bf16)(qc[i] * scale);
        }

        float m_run = 0.f, sum_run = 0.f;
        f32x4 xacc[2] = {{0.f, 0.f, 0.f, 0.f}, {0.f, 0.f, 0.f, 0.f}};

#pragma unroll
        for (int hh = 0; hh < 2; hh++) {
            const int NT = hh ? 13 : 12;    // tiles this half
            const int TB = hh ? 12 : 0;     // tile base
            const int NC = hh ? 7 : 6;      // 32-key chunks this half

            // ---- S^T = mfma(K, Q): lane holds S[q=lr][key=16(TB+t)+4lg+r]
            f32x4 s[13];
#pragma unroll
            for (int t = 0; t < NT; t++) {
                bf16x8 bk = *(const bf16x8*)&Ks[((TB + t) * 16 + lr) * KS_S + lg * 8];
                s[t] = __builtin_amdgcn_mfma_f32_16x16x32_bf16(
                    bk, aq, (f32x4){0.f, 0.f, 0.f, 0.f}, 0, 0, 0);
            }
            // ---- local max (tile 24 = s[12] valid only for lg<2)
            f32x4 vm = s[0];
#pragma unroll
            for (int t = 1; t < 12; t++) {
#pragma unroll
                for (int r = 0; r < 4; r++) vm[r] = fmaxf(vm[r], s[t][r]);
            }
            if (hh && lg < 2) {
#pragma unroll
                for (int r = 0; r < 4; r++) vm[r] = fmaxf(vm[r], s[12][r]);
            }
            float mh = fmaxf(fmaxf(vm[0], vm[1]), fmaxf(vm[2], vm[3]));
            mh = fmaxf(mh, __shfl_xor(mh, 16, 64));
            mh = fmaxf(mh, __shfl_xor(mh, 32, 64));

            float m_new = hh ? fmaxf(m_run, mh) : mh;
            if (hh) {
                float f = __expf(m_run - m_new);
                sum_run *= f;
                // rescale xacc rows (q = tile*16 + 4lg + r needs f of lane 4lg+r)
#pragma unroll
                for (int r = 0; r < 4; r++) {
                    float fr = __shfl(f, 4 * lg + r, 64);
                    xacc[0][r] *= fr;
                    xacc[1][r] *= fr;
                }
            }
            m_run = m_new;

            // ---- exp + sum
            f32x4 vsum = {0.f, 0.f, 0.f, 0.f};
#pragma unroll
            for (int t = 0; t < 12; t++) {
#pragma unroll
                for (int r = 0; r < 4; r++) {
                    float e = __expf(s[t][r] - m_new);
                    s[t][r] = e;
                    vsum[r] += e;
                }
            }
            if (hh) {
                if (lg < 2) {
#pragma unroll
                    for (int r = 0; r < 4; r++) {
                        float e = __expf(s[12][r] - m_new);
                        s[12][r] = e;
                        vsum[r] += e;
                    }
                } else {
#pragma unroll
                    for (int r = 0; r < 4; r++) s[12][r] = 0.f;
                }
            }
            float sumh = (vsum[0] + vsum[1]) + (vsum[2] + vsum[3]);
            sumh += __shfl_xor(sumh, 16, 64);
            sumh += __shfl_xor(sumh, 32, 64);
            sum_run += sumh;

            // ---- PV over this half's chunks: bounce P via LDS (b64 in/out)
#pragma unroll
            for (int c = 0; c < NC; c++) {
                uint2 wa, wb;
                wa.x = pkbf(s[2 * c][0], s[2 * c][1]);
                wa.y = pkbf(s[2 * c][2], s[2 * c][3]);
                if (2 * c + 1 < NT) {
                    wb.x = pkbf(s[2 * c + 1][0], s[2 * c + 1][1]);
                    wb.y = pkbf(s[2 * c + 1][2], s[2 * c + 1][3]);
                } else {
                    wb.x = 0u; wb.y = 0u;
                }
                *(uint2*)&pb[lr * PB_S + 4 * lg] = wa;
                *(uint2*)&pb[lr * PB_S + 16 + 4 * lg] = wb;
                bf16x4 lo = *(const bf16x4*)&pb[lr * PB_S + 8 * lg];
                bf16x4 hi = *(const bf16x4*)&pb[lr * PB_S + 8 * lg + 4];
                bf16x8 ap;
#pragma unroll
                for (int i = 0; i < 4; i++) { ap[i] = lo[i]; ap[4 + i] = hi[i]; }
                const int kbase = TB * 16 + c * 32;
#pragma unroll
                for (int nt = 0; nt < 2; nt++) {
                    bf16x8 bv = *(const bf16x8*)&Vs[(nt * 16 + lr) * VS_S + kbase + lg * 8];
                    xacc[nt] = __builtin_amdgcn_mfma_f32_16x16x32_bf16(ap, bv, xacc[nt], 0, 0, 0);
                }
            }
        }

        // ---- write out (RMW add onto conv output); rows q = tile*16+4lg+r
        float inv = 1.0f / sum_run;
#pragma unroll
        for (int r = 0; r < 4; r++) {
            float invr = __shfl(inv, 4 * lg + r, 64);
            int q = tile * 16 + 4 * lg + r;
            if (q < LTOK) {
                int rI = q / 7, c = q % 7;
                size_t base = ((size_t)b * NTOK + rI * WW + wi * WSP + c) * CCH + h * HDIM;
#pragma unroll
                for (int nt = 0; nt < 2; nt++)
                    out[base + nt * 16 + lr] += xacc[nt][r] * invr;
            }
        }
    }
}

// ---------------------------------------------------------------- launch
extern "C" void kernel_launch(void* const* d_in, const int* in_sizes, int n_in,
                              void* d_out, int out_size, void* d_ws, size_t ws_size,
                              hipStream_t stream) {
    const float* qkv = (const float*)d_in[0];
    const float* wconv = (const float*)d_in[1];
    const float* bconv = (const float*)d_in[2];
    float* out = (float*)d_out;
    char* ws = (char*)d_ws;

    const size_t WT_BYTES = (size_t)9 * CCH * CCH * 2;
    if (ws_size < WT_BYTES) return;
    __bf16* Wt = (__bf16*)ws;

    pack_w<<<(9 * CCH * CCH + 255) / 256, 256, 0, stream>>>(wconv, Wt);
    lepe_conv<<<NWIN * 7, 256, 0, stream>>>(qkv, Wt, bconv, out);
    attn2<<<NWIN * NHEADS, 512, 0, stream>>>(qkv, out);
}

// Round 6
// 405.573 us; speedup vs baseline: 1.0030x; 1.0030x over previous
//
#include <hip/hip_runtime.h>
#include <cmath>
#include <cstdint>

#define NBATCH 16
#define HH 56
#define WW 56
#define CCH 256
#define NHEADS 8
#define HDIM 32
#define WSP 7
#define NWIN 128
#define LTOK 392
#define NTOK 3136

typedef __attribute__((ext_vector_type(8))) __bf16 bf16x8;
typedef __attribute__((ext_vector_type(4))) __bf16 bf16x4;
typedef __attribute__((ext_vector_type(4))) float f32x4;

static __device__ __forceinline__ uint32_t pkbf(float a, float b) {
    __bf16 x = (__bf16)a, y = (__bf16)b;
    uint16_t xu = __builtin_bit_cast(uint16_t, x);
    uint16_t yu = __builtin_bit_cast(uint16_t, y);
    return (uint32_t)xu | ((uint32_t)yu << 16);
}

// ---------------------------------------------------------------- pack W
__global__ __launch_bounds__(256) void pack_w(const float* __restrict__ w,
                                              __bf16* __restrict__ Wt) {
    int idx = blockIdx.x * blockDim.x + threadIdx.x;
    if (idx >= 9 * CCH * CCH) return;
    int tap = idx / (CCH * CCH);
    int rem = idx % (CCH * CCH);
    int co = rem / CCH, ci = rem % CCH;
    Wt[idx] = (__bf16)(w[(size_t)tap * CCH * CCH + (size_t)ci * CCH + co]);
}

// ---------------------------------------------------------------- LePE conv
// Implicit GEMM. Block = (window, 8-row stripe): M=56 pos (padded 64), N=256.
// A: halo rows in LDS [10][9][264]. B: per-wave async global_load_lds pipeline,
// double-buffered per-wave 4KB LDS slots, counted vmcnt(4), no K-loop barriers.
#define AV_R 10
#define AV_C 9
#define AV_S 264
__global__ __launch_bounds__(256, 2) void lepe_conv(const float* __restrict__ qkv,
        const __bf16* __restrict__ Wt, const float* __restrict__ bconv,
        float* __restrict__ out) {
    const int bid = blockIdx.x;
    const int win = bid / 7, rb = bid % 7;
    const int b = win >> 3, wi = win & 7;
    const int rbase = rb * 8;
    const int tid = threadIdx.x;
    const int lane = tid & 63, wv = tid >> 6;
    const int lr = lane & 15, lg = lane >> 4;
    __shared__ __bf16 Av[AV_R * AV_C * AV_S];   // 47,520 B
    __shared__ __bf16 Bs[2][4][2048];           // 32,768 B
    const float* vsrc = qkv + 2 * (size_t)NBATCH * NTOK * CCH;

    for (int t = tid; t < AV_R * AV_C * 64; t += 256) {
        int rr = t / (AV_C * 64);
        int rem = t % (AV_C * 64);
        int cc = rem / 64, chg = rem % 64;
        int ar = rbase + rr - 1, c = cc - 1;
        f32x4 v = {0.f, 0.f, 0.f, 0.f};
        if (ar >= 0 && ar < HH && c >= 0 && c < WSP) {
            int token = ar * WW + wi * WSP + c;
            v = *(const f32x4*)(vsrc + ((size_t)b * NTOK + token) * CCH + chg * 4);
        }
        bf16x4 w;
#pragma unroll
        for (int i = 0; i < 4; i++) w[i] = (__bf16)v[i];
        *(bf16x4*)&Av[(rr * AV_C + cc) * AV_S + chg * 4] = w;
    }
    __syncthreads();

    f32x4 acc[4][4];
#pragma unroll
    for (int i = 0; i < 4; i++)
#pragma unroll
        for (int j = 0; j < 4; j++) acc[i][j] = (f32x4){0.f, 0.f, 0.f, 0.f};

    int ab[4];
#pragma unroll
    for (int mt = 0; mt < 4; mt++) {
        int p = mt * 16 + lr; if (p > 55) p = 55;
        ab[mt] = ((p / 7) * AV_C + (p % 7)) * AV_S + lg * 8;
    }
    int bro[4];
#pragma unroll
    for (int nt = 0; nt < 4; nt++)
        bro[nt] = (nt * 16 + lr) * 32 + ((lg ^ ((lr >> 1) & 3)) * 8);
    const __bf16* wsrc = Wt + (size_t)(wv * 64 + (lane >> 2)) * CCH
                            + (((lane & 3) ^ ((lane >> 3) & 3)) * 8);
    __bf16* b0 = &Bs[0][wv][0];
    __bf16* b1 = &Bs[1][wv][0];

#define GLDS(gp, lp)                                                        \
    __builtin_amdgcn_global_load_lds(                                       \
        (const __attribute__((address_space(1))) void*)(gp),                \
        (__attribute__((address_space(3))) void*)(lp), 16, 0, 0)
#define ISSUE(s, lb) do {                                                   \
        const int tp_ = (s) >> 3, kq_ = (s) & 7;                            \
        const __bf16* g_ = wsrc + tp_ * (CCH * CCH) + kq_ * 32;             \
        GLDS(g_, lb);                                                       \
        GLDS(g_ + 16 * CCH, (lb) + 512);                                    \
        GLDS(g_ + 32 * CCH, (lb) + 1024);                                   \
        GLDS(g_ + 48 * CCH, (lb) + 1536);                                   \
    } while (0)
#define STEPX(s, lb, doiss, s2) do {                                        \
        const int tap_ = (s) >> 3, ks_ = (s) & 7;                           \
        const int dy_ = (tap_ >= 6) ? 2 : ((tap_ >= 3) ? 1 : 0);            \
        const int offa = (tap_ + 6 * dy_) * AV_S + ks_ * 32;                \
        bf16x8 a_[4], bb_[4];                                               \
        _Pragma("unroll")                                                   \
        for (int mt = 0; mt < 4; mt++)                                      \
            a_[mt] = *(const bf16x8*)&Av[ab[mt] + offa];                    \
        _Pragma("unroll")                                                   \
        for (int nt = 0; nt < 4; nt++)                                      \
            bb_[nt] = *(const bf16x8*)&(lb)[bro[nt]];                       \
        asm volatile("s_waitcnt lgkmcnt(0)" ::: "memory");                  \
        __builtin_amdgcn_sched_barrier(0);                                  \
        if (doiss) ISSUE(s2, lb);                                           \
        _Pragma("unroll")                                                   \
        for (int mt = 0; mt < 4; mt++)                                      \
            _Pragma("unroll")                                               \
            for (int nt = 0; nt < 4; nt++)                                  \
                acc[mt][nt] = __builtin_amdgcn_mfma_f32_16x16x32_bf16(      \
                    a_[mt], bb_[nt], acc[mt][nt], 0, 0, 0);                 \
    } while (0)
#define WAIT4 asm volatile("s_waitcnt vmcnt(4)" ::: "memory")
#define WAIT0 asm volatile("s_waitcnt vmcnt(0)" ::: "memory")

    ISSUE(0, b0);
    ISSUE(1, b1);
    for (int s = 0; s < 70; s += 2) {
        WAIT4; STEPX(s, b0, 1, s + 2);
        WAIT4; STEPX(s + 1, b1, 1, s + 3);
    }
    WAIT4; STEPX(70, b0, 0, 0);
    WAIT0; STEPX(71, b1, 0, 0);
#undef GLDS
#undef ISSUE
#undef STEPX
#undef WAIT4
#undef WAIT0

#pragma unroll
    for (int nt = 0; nt < 4; nt++) {
        int ch = wv * 64 + nt * 16 + lr;
        float bias = bconv[ch];
#pragma unroll
        for (int mt = 0; mt < 4; mt++) {
#pragma unroll
            for (int r = 0; r < 4; r++) {
                int p = mt * 16 + lg * 4 + r;
                if (p < 56) {
                    int ar = rbase + p / 7, c = p % 7;
                    int token = ar * WW + wi * WSP + c;
                    out[((size_t)b * NTOK + token) * CCH + ch] = acc[mt][nt][r] + bias;
                }
            }
        }
    }
}

// ---------------------------------------------------------------- attention
// One block per (win, head), 8 waves, K/V^T staged once (f32->bf16 fused).
// SWAPPED QK^T: s = mfma(K_frag, Q_frag) -> lane owns full q-row (q=lr).
// Keys in two MACRO-EXPANDED halves (literal constants -> all s[] indexing
// static, stays in VGPRs; round-5 lesson: unroll pragma on the half loop was
// ignored -> dynamic indexing -> scratch). Online rescale between halves.
#define KS_R 400
#define KS_S 36
#define VS_S 424
#define PB_S 36
__global__ __launch_bounds__(512, 4) void attn2(const float* __restrict__ qkv,
                                                float* __restrict__ out) {
    const int wh = blockIdx.x;
    const int win = wh >> 3, h = wh & 7;
    const int b = win >> 3, wi = win & 7;
    const int tid = threadIdx.x;
    const int lane = tid & 63, wv = tid >> 6;
    const int lr = lane & 15, lg = lane >> 4;
    const float scale = 0.17677669529663687f;   // 32^-0.5

    __shared__ __bf16 Ks[KS_R * KS_S];          // 28,800 B
    __shared__ __bf16 Vs[HDIM * VS_S];          // 27,136 B
    __shared__ __bf16 Pb[8][16 * PB_S];         //  9,216 B  (total 65,152)

    const size_t plane = (size_t)NBATCH * NTOK * CCH;
    const float* qsrc = qkv + ((size_t)b * NTOK) * CCH + h * HDIM;
    const float* ksrc = qsrc + plane;
    const float* vsrc = qsrc + 2 * plane;

    // ---- stage K: [400 rows][32 ch], rows >=392 zero
    for (int t = tid; t < KS_R * 4; t += 512) {
        int row = t >> 2, g = t & 3;
        bf16x8 val;
        if (row < LTOK) {
            int tok = (row / 7) * WW + wi * WSP + row % 7;
            const float* p = ksrc + (size_t)tok * CCH + g * 8;
            f32x4 a = *(const f32x4*)p;
            f32x4 c = *(const f32x4*)(p + 4);
#pragma unroll
            for (int i = 0; i < 4; i++) { val[i] = (__bf16)a[i]; val[4 + i] = (__bf16)c[i]; }
        } else {
#pragma unroll
            for (int i = 0; i < 8; i++) val[i] = (__bf16)0.0f;
        }
        *(bf16x8*)&Ks[row * KS_S + g * 8] = val;
    }
    // ---- stage V transposed: Vs[ch][key]
    for (int t = tid; t < LTOK * 4; t += 512) {
        int key = t % LTOK, chg = t / LTOK;
        int tok = (key / 7) * WW + wi * WSP + key % 7;
        const float* p = vsrc + (size_t)tok * CCH + chg * 8;
        f32x4 a = *(const f32x4*)p;
        f32x4 c = *(const f32x4*)(p + 4);
#pragma unroll
        for (int i = 0; i < 4; i++) {
            Vs[(chg * 8 + i) * VS_S + key] = (__bf16)a[i];
            Vs[(chg * 8 + 4 + i) * VS_S + key] = (__bf16)c[i];
        }
    }
    // zero V pad keys 392..423
    for (int t = tid; t < HDIM * 32; t += 512) {
        int ch = t >> 5, k = t & 31;
        Vs[ch * VS_S + LTOK + k] = (__bf16)0.0f;
    }
    __syncthreads();

    __bf16* pb = Pb[wv];
    for (int tile = wv; tile < 25; tile += 8) {
        // ---- Q fragment (B-operand): lane holds q-col = lr, d = 8*lg+i
        int qrow = tile * 16 + lr;
        int qe = qrow < LTOK ? qrow : LTOK - 1;
        int tokq = (qe / 7) * WW + wi * WSP + qe % 7;
        const float* qp = qsrc + (size_t)tokq * CCH + lg * 8;
        f32x4 qa = *(const f32x4*)qp;
        f32x4 qc = *(const f32x4*)(qp + 4);
        bf16x8 aq;
#pragma unroll
        for (int i = 0; i < 4; i++) {
            aq[i] = (__bf16)(qa[i] * scale);
            aq[4 + i] = (__bf16)(qc[i] * scale);
        }

        float m_run = 0.f, sum_run = 0.f;
        f32x4 xacc[2] = {{0.f, 0.f, 0.f, 0.f}, {0.f, 0.f, 0.f, 0.f}};

// One half-pass over key tiles [TB, TB+NT). All args are LITERALS so every
// s[] index is compile-time static (VGPR-resident, no scratch).
#define HALF_PASS(NT, TB, NC, FIRST) do {                                   \
    f32x4 s[NT];                                                            \
    _Pragma("unroll")                                                       \
    for (int t = 0; t < NT; t++) {                                          \
        bf16x8 bk = *(const bf16x8*)&Ks[((TB + t) * 16 + lr) * KS_S + lg * 8]; \
        s[t] = __builtin_amdgcn_mfma_f32_16x16x32_bf16(                     \
            bk, aq, (f32x4){0.f, 0.f, 0.f, 0.f}, 0, 0, 0);                  \
    }                                                                       \
    f32x4 vm = s[0];                                                        \
    _Pragma("unroll")                                                       \
    for (int t = 1; t < 12; t++) {                                          \
        _Pragma("unroll")                                                   \
        for (int r = 0; r < 4; r++) vm[r] = fmaxf(vm[r], s[t][r]);          \
    }                                                                       \
    if (NT == 13 && lg < 2) {                                               \
        _Pragma("unroll")                                                   \
        for (int r = 0; r < 4; r++) vm[r] = fmaxf(vm[r], s[NT - 1][r]);     \
    }                                                                       \
    float mh = fmaxf(fmaxf(vm[0], vm[1]), fmaxf(vm[2], vm[3]));             \
    mh = fmaxf(mh, __shfl_xor(mh, 16, 64));                                 \
    mh = fmaxf(mh, __shfl_xor(mh, 32, 64));                                 \
    float m_new = FIRST ? mh : fmaxf(m_run, mh);                            \
    if (!FIRST) {                                                           \
        float f = __expf(m_run - m_new);                                    \
        sum_run *= f;                                                       \
        _Pragma("unroll")                                                   \
        for (int r = 0; r < 4; r++) {                                       \
            float fr = __shfl(f, 4 * lg + r, 64);                           \
            xacc[0][r] *= fr;                                               \
            xacc[1][r] *= fr;                                               \
        }                                                                   \
    }                                                                       \
    m_run = m_new;                                                          \
    f32x4 vsum = {0.f, 0.f, 0.f, 0.f};                                      \
    _Pragma("unroll")                                                       \
    for (int t = 0; t < 12; t++) {                                          \
        _Pragma("unroll")                                                   \
        for (int r = 0; r < 4; r++) {                                       \
            float e = __expf(s[t][r] - m_new);                              \
            s[t][r] = e;                                                    \
            vsum[r] += e;                                                   \
        }                                                                   \
    }                                                                       \
    if (NT == 13) {                                                         \
        if (lg < 2) {                                                       \
            _Pragma("unroll")                                               \
            for (int r = 0; r < 4; r++) {                                   \
                float e = __expf(s[NT - 1][r] - m_new);                     \
                s[NT - 1][r] = e;                                           \
                vsum[r] += e;                                               \
            }                                                               \
        } else {                                                            \
            _Pragma("unroll")                                               \
            for (int r = 0; r < 4; r++) s[NT - 1][r] = 0.f;                 \
        }                                                                   \
    }                                                                       \
    float sumh = (vsum[0] + vsum[1]) + (vsum[2] + vsum[3]);                 \
    sumh += __shfl_xor(sumh, 16, 64);                                       \
    sumh += __shfl_xor(sumh, 32, 64);                                       \
    sum_run += sumh;                                                        \
    _Pragma("unroll")                                                       \
    for (int c = 0; c < NC; c++) {                                          \
        uint2 wa, wb;                                                       \
        wa.x = pkbf(s[2 * c][0], s[2 * c][1]);                              \
        wa.y = pkbf(s[2 * c][2], s[2 * c][3]);                              \
        if (2 * c + 1 < NT) {                                               \
            wb.x = pkbf(s[2 * c + 1][0], s[2 * c + 1][1]);                  \
            wb.y = pkbf(s[2 * c + 1][2], s[2 * c + 1][3]);                  \
        } else {                                                            \
            wb.x = 0u; wb.y = 0u;                                           \
        }                                                                   \
        *(uint2*)&pb[lr * PB_S + 4 * lg] = wa;                              \
        *(uint2*)&pb[lr * PB_S + 16 + 4 * lg] = wb;                         \
        bf16x4 lo = *(const bf16x4*)&pb[lr * PB_S + 8 * lg];                \
        bf16x4 hi = *(const bf16x4*)&pb[lr * PB_S + 8 * lg + 4];            \
        bf16x8 ap;                                                          \
        _Pragma("unroll")                                                   \
        for (int i = 0; i < 4; i++) { ap[i] = lo[i]; ap[4 + i] = hi[i]; }   \
        const int kbase = TB * 16 + c * 32;                                 \
        _Pragma("unroll")                                                   \
        for (int nt = 0; nt < 2; nt++) {                                    \
            bf16x8 bv = *(const bf16x8*)&Vs[(nt * 16 + lr) * VS_S + kbase + lg * 8]; \
            xacc[nt] = __builtin_amdgcn_mfma_f32_16x16x32_bf16(             \
                ap, bv, xacc[nt], 0, 0, 0);                                 \
        }                                                                   \
    }                                                                       \
} while (0)

        HALF_PASS(12, 0, 6, 1);
        HALF_PASS(13, 12, 7, 0);
#undef HALF_PASS

        // ---- write out (RMW add onto conv output); rows q = tile*16+4lg+r
        float inv = 1.0f / sum_run;
#pragma unroll
        for (int r = 0; r < 4; r++) {
            float invr = __shfl(inv, 4 * lg + r, 64);
            int q = tile * 16 + 4 * lg + r;
            if (q < LTOK) {
                int rI = q / 7, c = q % 7;
                size_t base = ((size_t)b * NTOK + rI * WW + wi * WSP + c) * CCH + h * HDIM;
#pragma unroll
                for (int nt = 0; nt < 2; nt++)
                    out[base + nt * 16 + lr] += xacc[nt][r] * invr;
            }
        }
    }
}

// ---------------------------------------------------------------- launch
extern "C" void kernel_launch(void* const* d_in, const int* in_sizes, int n_in,
                              void* d_out, int out_size, void* d_ws, size_t ws_size,
                              hipStream_t stream) {
    const float* qkv = (const float*)d_in[0];
    const float* wconv = (const float*)d_in[1];
    const float* bconv = (const float*)d_in[2];
    float* out = (float*)d_out;
    char* ws = (char*)d_ws;

    const size_t WT_BYTES = (size_t)9 * CCH * CCH * 2;
    if (ws_size < WT_BYTES) return;
    __bf16* Wt = (__bf16*)ws;

    pack_w<<<(9 * CCH * CCH + 255) / 256, 256, 0, stream>>>(wconv, Wt);
    lepe_conv<<<NWIN * 7, 256, 0, stream>>>(qkv, Wt, bconv, out);
    attn2<<<NWIN * NHEADS, 512, 0, stream>>>(qkv, out);
}

// Round 7
// 242.861 us; speedup vs baseline: 1.6751x; 1.6700x over previous
//
#include <hip/hip_runtime.h>
#include <cmath>
#include <cstdint>

#define NBATCH 16
#define HH 56
#define WW 56
#define CCH 256
#define NHEADS 8
#define HDIM 32
#define WSP 7
#define NWIN 128
#define LTOK 392
#define NTOK 3136

typedef __attribute__((ext_vector_type(8))) __bf16 bf16x8;
typedef __attribute__((ext_vector_type(4))) __bf16 bf16x4;
typedef __attribute__((ext_vector_type(4))) float f32x4;

static __device__ __forceinline__ uint32_t pkbf(float a, float b) {
    __bf16 x = (__bf16)a, y = (__bf16)b;
    uint16_t xu = __builtin_bit_cast(uint16_t, x);
    uint16_t yu = __builtin_bit_cast(uint16_t, y);
    return (uint32_t)xu | ((uint32_t)yu << 16);
}

// ---------------------------------------------------------------- pack W
__global__ __launch_bounds__(256) void pack_w(const float* __restrict__ w,
                                              __bf16* __restrict__ Wt) {
    int idx = blockIdx.x * blockDim.x + threadIdx.x;
    if (idx >= 9 * CCH * CCH) return;
    int tap = idx / (CCH * CCH);
    int rem = idx % (CCH * CCH);
    int co = rem / CCH, ci = rem % CCH;
    Wt[idx] = (__bf16)(w[(size_t)tap * CCH * CCH + (size_t)ci * CCH + co]);
}

// ---------------------------------------------------------------- LePE conv
// Implicit GEMM. Block = (window, 8-row stripe): M=56 pos (padded 64), N=256.
// A: halo rows in LDS [10][9][264]. B: per-wave async global_load_lds pipeline,
// double-buffered per-wave 4KB LDS slots, counted vmcnt(4), no K-loop barriers.
#define AV_R 10
#define AV_C 9
#define AV_S 264
__global__ __launch_bounds__(256, 2) void lepe_conv(const float* __restrict__ qkv,
        const __bf16* __restrict__ Wt, const float* __restrict__ bconv,
        float* __restrict__ out) {
    const int bid = blockIdx.x;
    const int win = bid / 7, rb = bid % 7;
    const int b = win >> 3, wi = win & 7;
    const int rbase = rb * 8;
    const int tid = threadIdx.x;
    const int lane = tid & 63, wv = tid >> 6;
    const int lr = lane & 15, lg = lane >> 4;
    __shared__ __bf16 Av[AV_R * AV_C * AV_S];   // 47,520 B
    __shared__ __bf16 Bs[2][4][2048];           // 32,768 B
    const float* vsrc = qkv + 2 * (size_t)NBATCH * NTOK * CCH;

    for (int t = tid; t < AV_R * AV_C * 64; t += 256) {
        int rr = t / (AV_C * 64);
        int rem = t % (AV_C * 64);
        int cc = rem / 64, chg = rem % 64;
        int ar = rbase + rr - 1, c = cc - 1;
        f32x4 v = {0.f, 0.f, 0.f, 0.f};
        if (ar >= 0 && ar < HH && c >= 0 && c < WSP) {
            int token = ar * WW + wi * WSP + c;
            v = *(const f32x4*)(vsrc + ((size_t)b * NTOK + token) * CCH + chg * 4);
        }
        bf16x4 w;
#pragma unroll
        for (int i = 0; i < 4; i++) w[i] = (__bf16)v[i];
        *(bf16x4*)&Av[(rr * AV_C + cc) * AV_S + chg * 4] = w;
    }
    __syncthreads();

    f32x4 acc[4][4];
#pragma unroll
    for (int i = 0; i < 4; i++)
#pragma unroll
        for (int j = 0; j < 4; j++) acc[i][j] = (f32x4){0.f, 0.f, 0.f, 0.f};

    int ab[4];
#pragma unroll
    for (int mt = 0; mt < 4; mt++) {
        int p = mt * 16 + lr; if (p > 55) p = 55;
        ab[mt] = ((p / 7) * AV_C + (p % 7)) * AV_S + lg * 8;
    }
    int bro[4];
#pragma unroll
    for (int nt = 0; nt < 4; nt++)
        bro[nt] = (nt * 16 + lr) * 32 + ((lg ^ ((lr >> 1) & 3)) * 8);
    const __bf16* wsrc = Wt + (size_t)(wv * 64 + (lane >> 2)) * CCH
                            + (((lane & 3) ^ ((lane >> 3) & 3)) * 8);
    __bf16* b0 = &Bs[0][wv][0];
    __bf16* b1 = &Bs[1][wv][0];

#define GLDS(gp, lp)                                                        \
    __builtin_amdgcn_global_load_lds(                                       \
        (const __attribute__((address_space(1))) void*)(gp),                \
        (__attribute__((address_space(3))) void*)(lp), 16, 0, 0)
#define ISSUE(s, lb) do {                                                   \
        const int tp_ = (s) >> 3, kq_ = (s) & 7;                            \
        const __bf16* g_ = wsrc + tp_ * (CCH * CCH) + kq_ * 32;             \
        GLDS(g_, lb);                                                       \
        GLDS(g_ + 16 * CCH, (lb) + 512);                                    \
        GLDS(g_ + 32 * CCH, (lb) + 1024);                                   \
        GLDS(g_ + 48 * CCH, (lb) + 1536);                                   \
    } while (0)
#define STEPX(s, lb, doiss, s2) do {                                        \
        const int tap_ = (s) >> 3, ks_ = (s) & 7;                           \
        const int dy_ = (tap_ >= 6) ? 2 : ((tap_ >= 3) ? 1 : 0);            \
        const int offa = (tap_ + 6 * dy_) * AV_S + ks_ * 32;                \
        bf16x8 a_[4], bb_[4];                                               \
        _Pragma("unroll")                                                   \
        for (int mt = 0; mt < 4; mt++)                                      \
            a_[mt] = *(const bf16x8*)&Av[ab[mt] + offa];                    \
        _Pragma("unroll")                                                   \
        for (int nt = 0; nt < 4; nt++)                                      \
            bb_[nt] = *(const bf16x8*)&(lb)[bro[nt]];                       \
        asm volatile("s_waitcnt lgkmcnt(0)" ::: "memory");                  \
        __builtin_amdgcn_sched_barrier(0);                                  \
        if (doiss) ISSUE(s2, lb);                                           \
        _Pragma("unroll")                                                   \
        for (int mt = 0; mt < 4; mt++)                                      \
            _Pragma("unroll")                                               \
            for (int nt = 0; nt < 4; nt++)                                  \
                acc[mt][nt] = __builtin_amdgcn_mfma_f32_16x16x32_bf16(      \
                    a_[mt], bb_[nt], acc[mt][nt], 0, 0, 0);                 \
    } while (0)
#define WAIT4 asm volatile("s_waitcnt vmcnt(4)" ::: "memory")
#define WAIT0 asm volatile("s_waitcnt vmcnt(0)" ::: "memory")

    ISSUE(0, b0);
    ISSUE(1, b1);
    for (int s = 0; s < 70; s += 2) {
        WAIT4; STEPX(s, b0, 1, s + 2);
        WAIT4; STEPX(s + 1, b1, 1, s + 3);
    }
    WAIT4; STEPX(70, b0, 0, 0);
    WAIT0; STEPX(71, b1, 0, 0);
#undef GLDS
#undef ISSUE
#undef STEPX
#undef WAIT4
#undef WAIT0

#pragma unroll
    for (int nt = 0; nt < 4; nt++) {
        int ch = wv * 64 + nt * 16 + lr;
        float bias = bconv[ch];
#pragma unroll
        for (int mt = 0; mt < 4; mt++) {
#pragma unroll
            for (int r = 0; r < 4; r++) {
                int p = mt * 16 + lg * 4 + r;
                if (p < 56) {
                    int ar = rbase + p / 7, c = p % 7;
                    int token = ar * WW + wi * WSP + c;
                    out[((size_t)b * NTOK + token) * CCH + ch] = acc[mt][nt][r] + bias;
                }
            }
        }
    }
}

// ---------------------------------------------------------------- attention
// One block per (win, head), 8 waves, K/V^T staged once (f32->bf16 fused).
// SWAPPED QK^T: s = mfma(K_frag, Q_frag) -> lane owns full q-row (q=lr).
// Two macro-expanded key halves (static s[] indexing) with online rescale.
// launch_bounds(512, 2): LDS already caps at 2 blocks/CU; declaring 2 raises
// the VGPR cap 64 -> 128 (round-6 lesson: (512,4) capped VGPRs at 64 ->
// ~750 MB/dispatch of scratch spill traffic, MfmaUtil 2.6%).
#define KS_R 400
#define KS_S 36
#define VS_S 424
#define PB_S 36
__global__ __launch_bounds__(512, 2) void attn2(const float* __restrict__ qkv,
                                                float* __restrict__ out) {
    const int wh = blockIdx.x;
    const int win = wh >> 3, h = wh & 7;
    const int b = win >> 3, wi = win & 7;
    const int tid = threadIdx.x;
    const int lane = tid & 63, wv = tid >> 6;
    const int lr = lane & 15, lg = lane >> 4;
    const float scale = 0.17677669529663687f;   // 32^-0.5

    __shared__ __bf16 Ks[KS_R * KS_S];          // 28,800 B
    __shared__ __bf16 Vs[HDIM * VS_S];          // 27,136 B
    __shared__ __bf16 Pb[8][16 * PB_S];         //  9,216 B  (total 65,152)

    const size_t plane = (size_t)NBATCH * NTOK * CCH;
    const float* qsrc = qkv + ((size_t)b * NTOK) * CCH + h * HDIM;
    const float* ksrc = qsrc + plane;
    const float* vsrc = qsrc + 2 * plane;

    // ---- stage K: [400 rows][32 ch], rows >=392 zero
    for (int t = tid; t < KS_R * 4; t += 512) {
        int row = t >> 2, g = t & 3;
        bf16x8 val;
        if (row < LTOK) {
            int tok = (row / 7) * WW + wi * WSP + row % 7;
            const float* p = ksrc + (size_t)tok * CCH + g * 8;
            f32x4 a = *(const f32x4*)p;
            f32x4 c = *(const f32x4*)(p + 4);
#pragma unroll
            for (int i = 0; i < 4; i++) { val[i] = (__bf16)a[i]; val[4 + i] = (__bf16)c[i]; }
        } else {
#pragma unroll
            for (int i = 0; i < 8; i++) val[i] = (__bf16)0.0f;
        }
        *(bf16x8*)&Ks[row * KS_S + g * 8] = val;
    }
    // ---- stage V transposed: Vs[ch][key]
    for (int t = tid; t < LTOK * 4; t += 512) {
        int key = t % LTOK, chg = t / LTOK;
        int tok = (key / 7) * WW + wi * WSP + key % 7;
        const float* p = vsrc + (size_t)tok * CCH + chg * 8;
        f32x4 a = *(const f32x4*)p;
        f32x4 c = *(const f32x4*)(p + 4);
#pragma unroll
        for (int i = 0; i < 4; i++) {
            Vs[(chg * 8 + i) * VS_S + key] = (__bf16)a[i];
            Vs[(chg * 8 + 4 + i) * VS_S + key] = (__bf16)c[i];
        }
    }
    // zero V pad keys 392..423
    for (int t = tid; t < HDIM * 32; t += 512) {
        int ch = t >> 5, k = t & 31;
        Vs[ch * VS_S + LTOK + k] = (__bf16)0.0f;
    }
    __syncthreads();

    __bf16* pb = Pb[wv];
    for (int tile = wv; tile < 25; tile += 8) {
        // ---- Q fragment (B-operand): lane holds q-col = lr, d = 8*lg+i
        int qrow = tile * 16 + lr;
        int qe = qrow < LTOK ? qrow : LTOK - 1;
        int tokq = (qe / 7) * WW + wi * WSP + qe % 7;
        const float* qp = qsrc + (size_t)tokq * CCH + lg * 8;
        f32x4 qa = *(const f32x4*)qp;
        f32x4 qc = *(const f32x4*)(qp + 4);
        bf16x8 aq;
#pragma unroll
        for (int i = 0; i < 4; i++) {
            aq[i] = (__bf16)(qa[i] * scale);
            aq[4 + i] = (__bf16)(qc[i] * scale);
        }

        float m_run = 0.f, sum_run = 0.f;
        f32x4 xacc[2] = {{0.f, 0.f, 0.f, 0.f}, {0.f, 0.f, 0.f, 0.f}};

// One half-pass over key tiles [TB, TB+NT). All args are LITERALS so every
// s[] index is compile-time static (VGPR-resident, no scratch).
#define HALF_PASS(NT, TB, NC, FIRST) do {                                   \
    f32x4 s[NT];                                                            \
    _Pragma("unroll")                                                       \
    for (int t = 0; t < NT; t++) {                                          \
        bf16x8 bk = *(const bf16x8*)&Ks[((TB + t) * 16 + lr) * KS_S + lg * 8]; \
        s[t] = __builtin_amdgcn_mfma_f32_16x16x32_bf16(                     \
            bk, aq, (f32x4){0.f, 0.f, 0.f, 0.f}, 0, 0, 0);                  \
    }                                                                       \
    f32x4 vm = s[0];                                                        \
    _Pragma("unroll")                                                       \
    for (int t = 1; t < 12; t++) {                                          \
        _Pragma("unroll")                                                   \
        for (int r = 0; r < 4; r++) vm[r] = fmaxf(vm[r], s[t][r]);          \
    }                                                                       \
    if (NT == 13 && lg < 2) {                                               \
        _Pragma("unroll")                                                   \
        for (int r = 0; r < 4; r++) vm[r] = fmaxf(vm[r], s[NT - 1][r]);     \
    }                                                                       \
    float mh = fmaxf(fmaxf(vm[0], vm[1]), fmaxf(vm[2], vm[3]));             \
    mh = fmaxf(mh, __shfl_xor(mh, 16, 64));                                 \
    mh = fmaxf(mh, __shfl_xor(mh, 32, 64));                                 \
    float m_new = FIRST ? mh : fmaxf(m_run, mh);                            \
    if (!FIRST) {                                                           \
        float f = __expf(m_run - m_new);                                    \
        sum_run *= f;                                                       \
        _Pragma("unroll")                                                   \
        for (int r = 0; r < 4; r++) {                                       \
            float fr = __shfl(f, 4 * lg + r, 64);                           \
            xacc[0][r] *= fr;                                               \
            xacc[1][r] *= fr;                                               \
        }                                                                   \
    }                                                                       \
    m_run = m_new;                                                          \
    f32x4 vsum = {0.f, 0.f, 0.f, 0.f};                                      \
    _Pragma("unroll")                                                       \
    for (int t = 0; t < 12; t++) {                                          \
        _Pragma("unroll")                                                   \
        for (int r = 0; r < 4; r++) {                                       \
            float e = __expf(s[t][r] - m_new);                              \
            s[t][r] = e;                                                    \
            vsum[r] += e;                                                   \
        }                                                                   \
    }                                                                       \
    if (NT == 13) {                                                         \
        if (lg < 2) {                                                       \
            _Pragma("unroll")                                               \
            for (int r = 0; r < 4; r++) {                                   \
                float e = __expf(s[NT - 1][r] - m_new);                     \
                s[NT - 1][r] = e;                                           \
                vsum[r] += e;                                               \
            }                                                               \
        } else {                                                            \
            _Pragma("unroll")                                               \
            for (int r = 0; r < 4; r++) s[NT - 1][r] = 0.f;                 \
        }                                                                   \
    }                                                                       \
    float sumh = (vsum[0] + vsum[1]) + (vsum[2] + vsum[3]);                 \
    sumh += __shfl_xor(sumh, 16, 64);                                       \
    sumh += __shfl_xor(sumh, 32, 64);                                       \
    sum_run += sumh;                                                        \
    _Pragma("unroll")                                                       \
    for (int c = 0; c < NC; c++) {                                          \
        uint2 wa, wb;                                                       \
        wa.x = pkbf(s[2 * c][0], s[2 * c][1]);                              \
        wa.y = pkbf(s[2 * c][2], s[2 * c][3]);                              \
        if (2 * c + 1 < NT) {                                               \
            wb.x = pkbf(s[2 * c + 1][0], s[2 * c + 1][1]);                  \
            wb.y = pkbf(s[2 * c + 1][2], s[2 * c + 1][3]);                  \
        } else {                                                            \
            wb.x = 0u; wb.y = 0u;                                           \
        }                                                                   \
        *(uint2*)&pb[lr * PB_S + 4 * lg] = wa;                              \
        *(uint2*)&pb[lr * PB_S + 16 + 4 * lg] = wb;                         \
        bf16x4 lo = *(const bf16x4*)&pb[lr * PB_S + 8 * lg];                \
        bf16x4 hi = *(const bf16x4*)&pb[lr * PB_S + 8 * lg + 4];            \
        bf16x8 ap;                                                          \
        _Pragma("unroll")                                                   \
        for (int i = 0; i < 4; i++) { ap[i] = lo[i]; ap[4 + i] = hi[i]; }   \
        const int kbase = TB * 16 + c * 32;                                 \
        _Pragma("unroll")                                                   \
        for (int nt = 0; nt < 2; nt++) {                                    \
            bf16x8 bv = *(const bf16x8*)&Vs[(nt * 16 + lr) * VS_S + kbase + lg * 8]; \
            xacc[nt] = __builtin_amdgcn_mfma_f32_16x16x32_bf16(             \
                ap, bv, xacc[nt], 0, 0, 0);                                 \
        }                                                                   \
    }                                                                       \
} while (0)

        HALF_PASS(12, 0, 6, 1);
        HALF_PASS(13, 12, 7, 0);
#undef HALF_PASS

        // ---- write out (RMW add onto conv output); rows q = tile*16+4lg+r
        float inv = 1.0f / sum_run;
#pragma unroll
        for (int r = 0; r < 4; r++) {
            float invr = __shfl(inv, 4 * lg + r, 64);
            int q = tile * 16 + 4 * lg + r;
            if (q < LTOK) {
                int rI = q / 7, c = q % 7;
                size_t base = ((size_t)b * NTOK + rI * WW + wi * WSP + c) * CCH + h * HDIM;
#pragma unroll
                for (int nt = 0; nt < 2; nt++)
                    out[base + nt * 16 + lr] += xacc[nt][r] * invr;
            }
        }
    }
}

// ---------------------------------------------------------------- launch
extern "C" void kernel_launch(void* const* d_in, const int* in_sizes, int n_in,
                              void* d_out, int out_size, void* d_ws, size_t ws_size,
                              hipStream_t stream) {
    const float* qkv = (const float*)d_in[0];
    const float* wconv = (const float*)d_in[1];
    const float* bconv = (const float*)d_in[2];
    float* out = (float*)d_out;
    char* ws = (char*)d_ws;

    const size_t WT_BYTES = (size_t)9 * CCH * CCH * 2;
    if (ws_size < WT_BYTES) return;
    __bf16* Wt = (__bf16*)ws;

    pack_w<<<(9 * CCH * CCH + 255) / 256, 256, 0, stream>>>(wconv, Wt);
    lepe_conv<<<NWIN * 7, 256, 0, stream>>>(qkv, Wt, bconv, out);
    attn2<<<NWIN * NHEADS, 512, 0, stream>>>(qkv, out);
}